// Round 3
// baseline (231.259 us; speedup 1.0000x reference)
//
#include <hip/hip_runtime.h>
#include <hip/hip_bf16.h>

#define DIM 256
#define NSB 8
#define NLBL 64
#define NSEG (NSB * NLBL)
#define BPS 4   // blocks per segment for accum

// ---------------- k1: histogram (LDS bins) + fused last-block scan ----------------
__global__ void k_hist(const int* __restrict__ labels, const int* __restrict__ sbidx,
                       int* __restrict__ counts, int* __restrict__ done,
                       int* __restrict__ offsets, int* __restrict__ cursors,
                       float* __restrict__ Mvals, float* __restrict__ invcnt, int n) {
    __shared__ int bins[NSEG];
    __shared__ int lastFlag;
    for (int i = threadIdx.x; i < NSEG; i += blockDim.x) bins[i] = 0;
    __syncthreads();
    int t4 = blockIdx.x * blockDim.x + threadIdx.x;
    int stride4 = gridDim.x * blockDim.x;
    for (int q = t4; q * 4 < n; q += stride4) {
        int4 lb = reinterpret_cast<const int4*>(labels)[q];
        int4 sb = reinterpret_cast<const int4*>(sbidx)[q];
        atomicAdd(&bins[sb.x * NLBL + lb.x], 1);
        atomicAdd(&bins[sb.y * NLBL + lb.y], 1);
        atomicAdd(&bins[sb.z * NLBL + lb.z], 1);
        atomicAdd(&bins[sb.w * NLBL + lb.w], 1);
    }
    __syncthreads();
    for (int i = threadIdx.x; i < NSEG; i += blockDim.x)
        if (bins[i] > 0) atomicAdd(&counts[i], bins[i]);
    __syncthreads();
    if (threadIdx.x == 0) {
        __threadfence();
        int t = atomicAdd(done, 1);
        lastFlag = (t == (int)gridDim.x - 1) ? 1 : 0;
    }
    __syncthreads();
    if (!lastFlag) return;
    if (threadIdx.x < 64) {       // exclusive scan over 512 counts, one wave
        int lane = threadIdx.x;
        int carry = 0;
        for (int c = 0; c < NSB; c++) {
            int idx = c * 64 + lane;
            int v = atomicAdd(&counts[idx], 0);   // coherent read (cross-XCD)
            int incl = v;
            #pragma unroll
            for (int m = 1; m < 64; m <<= 1) {
                int t2 = __shfl_up(incl, m, 64);
                if (lane >= m) incl += t2;
            }
            int excl = carry + incl - v;
            offsets[idx] = excl;
            cursors[idx] = excl;
            invcnt[idx] = 1.0f / fmaxf((float)v, 1.0f);
            carry += __shfl(incl, 63, 64);
            unsigned long long b = __ballot(v > 0);
            if (lane == 0) Mvals[c] = (float)__popcll(b);
        }
    }
}

// ---------------- k2: scatter point indices into sorted order ----------------
__global__ void k_scatter(const int* __restrict__ labels, const int* __restrict__ sbidx,
                          int* __restrict__ cursors, int* __restrict__ sorted, int n) {
    int t = blockIdx.x * blockDim.x + threadIdx.x;
    int stride = gridDim.x * blockDim.x;
    for (int q = t; q * 4 < n; q += stride) {
        int4 lb = reinterpret_cast<const int4*>(labels)[q];
        int4 sb = reinterpret_cast<const int4*>(sbidx)[q];
        int p = q * 4;
        sorted[atomicAdd(&cursors[sb.x * NLBL + lb.x], 1)] = p;
        sorted[atomicAdd(&cursors[sb.y * NLBL + lb.y], 1)] = p + 1;
        sorted[atomicAdd(&cursors[sb.z * NLBL + lb.z], 1)] = p + 2;
        sorted[atomicAdd(&cursors[sb.w * NLBL + lb.w], 1)] = p + 3;
    }
}

// ---------------- k3: gather rows per segment, normalize, accumulate (2-deep pipeline) ----------------
__global__ void k_accum(const float* __restrict__ outp, const int* __restrict__ sorted,
                        const int* __restrict__ offsets, const int* __restrict__ counts,
                        float* __restrict__ partials) {
    int seg = blockIdx.x >> 2;       // BPS = 4
    int part = blockIdx.x & 3;
    int base = offsets[seg], cnt = counts[seg];
    int chunk = (cnt + BPS - 1) / BPS;
    int lo = base + part * chunk;
    int hi = min(base + cnt, lo + chunk);
    int wv = threadIdx.x >> 6, lane = threadIdx.x & 63;
    float4 acc = {0.f, 0.f, 0.f, 0.f};
    int i = lo + wv * 2;
    int p0 = (i < hi) ? sorted[i] : -1;
    int p1 = (i + 1 < hi) ? sorted[i + 1] : -1;
    for (; i < hi; i += 8) {
        int ni = i + 8;
        int np0 = (ni < hi) ? sorted[ni] : -1;          // prefetch next ids
        int np1 = (ni + 1 < hi) ? sorted[ni + 1] : -1;
        float4 v0 = {0.f, 0.f, 0.f, 0.f}, v1 = {0.f, 0.f, 0.f, 0.f};
        v0 = *reinterpret_cast<const float4*>(outp + (size_t)p0 * DIM + lane * 4);
        if (p1 >= 0)
            v1 = *reinterpret_cast<const float4*>(outp + (size_t)p1 * DIM + lane * 4);
        float ss0 = v0.x * v0.x + v0.y * v0.y + v0.z * v0.z + v0.w * v0.w;
        float ss1 = v1.x * v1.x + v1.y * v1.y + v1.z * v1.z + v1.w * v1.w;
        #pragma unroll
        for (int m = 32; m >= 1; m >>= 1) {
            ss0 += __shfl_xor(ss0, m, 64);
            ss1 += __shfl_xor(ss1, m, 64);
        }
        float rn0 = 1.0f / (sqrtf(ss0) + 1e-8f);
        float rn1 = 1.0f / (sqrtf(ss1) + 1e-8f);
        acc.x += v0.x * rn0 + v1.x * rn1;   // invalid row is zeros -> contributes 0
        acc.y += v0.y * rn0 + v1.y * rn1;
        acc.z += v0.z * rn0 + v1.z * rn1;
        acc.w += v0.w * rn0 + v1.w * rn1;
        p0 = np0; p1 = np1;
    }
    __shared__ float pl[4][DIM];
    pl[wv][lane * 4 + 0] = acc.x;
    pl[wv][lane * 4 + 1] = acc.y;
    pl[wv][lane * 4 + 2] = acc.z;
    pl[wv][lane * 4 + 3] = acc.w;
    __syncthreads();
    int t = threadIdx.x;
    partials[(size_t)blockIdx.x * DIM + t] = pl[0][t] + pl[1][t] + pl[2][t] + pl[3][t];
}

// ---------------- k4: push term (mu recomputed from partials; chunk 0 materializes mus) ----------------
__global__ void k_push(const float* __restrict__ partials, const int* __restrict__ counts,
                       float* __restrict__ mus, float* __restrict__ pushv) {
    __shared__ float lds[NLBL][DIM + 1];
    int s = blockIdx.x >> 4;
    int chunk = blockIdx.x & 15;
    for (int i = threadIdx.x; i < NLBL * DIM; i += 256) {
        int r = i >> 8, d = i & 255;
        int segid = s * NLBL + r;
        const float* pp = partials + (size_t)segid * BPS * DIM + d;
        float sum = pp[0] + pp[DIM] + pp[2 * DIM] + pp[3 * DIM];
        float mu = sum / fmaxf((float)counts[segid], 1.0f);
        lds[r][d] = mu;
        if (chunk == 0) mus[(size_t)segid * DIM + d] = mu;
    }
    __syncthreads();
    int pair = chunk * 256 + threadIdx.x;
    int l1 = pair >> 6, l2 = pair & 63;
    float dist = 0.0f;
    #pragma unroll 8
    for (int d = 0; d < DIM; d++) dist += fabsf(lds[l1][d] - lds[l2][d]);
    float v = fmaxf(3.0f - dist, 0.0f);   // 2*DELTA_D
    v = v * v;
    bool ok = (l1 != l2) && (counts[s * NLBL + l1] > 0) && (counts[s * NLBL + l2] > 0);
    v = ok ? v : 0.0f;
    #pragma unroll
    for (int m = 32; m >= 1; m >>= 1) v += __shfl_xor(v, m, 64);
    __shared__ float wsum[4];
    if ((threadIdx.x & 63) == 0) wsum[threadIdx.x >> 6] = v;
    __syncthreads();
    if (threadIdx.x == 0) atomicAdd(&pushv[s], wsum[0] + wsum[1] + wsum[2] + wsum[3]);
}

// ---------------- k5: pull term, NATURAL ORDER stream (no gather of x), 2 rows/wave/iter ----------------
__global__ void k_pull(const float* __restrict__ outp, const int* __restrict__ labels,
                       const int* __restrict__ sbidx, const float* __restrict__ mus,
                       const float* __restrict__ invcnt, float* __restrict__ Lpull, int n) {
    __shared__ float lp[NSB];
    if (threadIdx.x < NSB) lp[threadIdx.x] = 0.f;
    __syncthreads();
    int gtid = blockIdx.x * blockDim.x + threadIdx.x;
    int w = gtid >> 6;
    int lane = threadIdx.x & 63;
    int nw = (gridDim.x * blockDim.x) >> 6;
    for (int p0 = w * 2; p0 < n; p0 += nw * 2) {
        int p1 = p0 + 1;
        bool has1 = p1 < n;
        float4 x0 = *reinterpret_cast<const float4*>(outp + (size_t)p0 * DIM + lane * 4);
        float4 x1 = {0.f, 0.f, 0.f, 0.f};
        if (has1) x1 = *reinterpret_cast<const float4*>(outp + (size_t)p1 * DIM + lane * 4);
        int seg0 = sbidx[p0] * NLBL + labels[p0];
        int seg1 = has1 ? (sbidx[p1] * NLBL + labels[p1]) : 0;
        float4 mu0 = *reinterpret_cast<const float4*>(mus + (size_t)seg0 * DIM + lane * 4);
        float4 mu1 = *reinterpret_cast<const float4*>(mus + (size_t)seg1 * DIM + lane * 4);
        float ss0 = x0.x * x0.x + x0.y * x0.y + x0.z * x0.z + x0.w * x0.w;
        float ss1 = x1.x * x1.x + x1.y * x1.y + x1.z * x1.z + x1.w * x1.w;
        #pragma unroll
        for (int m = 32; m >= 1; m >>= 1) {
            ss0 += __shfl_xor(ss0, m, 64);
            ss1 += __shfl_xor(ss1, m, 64);
        }
        float rn0 = 1.0f / (sqrtf(ss0) + 1e-8f);
        float rn1 = 1.0f / (sqrtf(ss1) + 1e-8f);
        float d10 = fabsf(mu0.x - x0.x * rn0) + fabsf(mu0.y - x0.y * rn0) +
                    fabsf(mu0.z - x0.z * rn0) + fabsf(mu0.w - x0.w * rn0);
        float d11 = fabsf(mu1.x - x1.x * rn1) + fabsf(mu1.y - x1.y * rn1) +
                    fabsf(mu1.z - x1.z * rn1) + fabsf(mu1.w - x1.w * rn1);
        #pragma unroll
        for (int m = 32; m >= 1; m >>= 1) {
            d10 += __shfl_xor(d10, m, 64);
            d11 += __shfl_xor(d11, m, 64);
        }
        if (lane == 0) {
            float t0 = fmaxf(d10 - 0.5f, 0.f);   // DELTA_V
            atomicAdd(&lp[seg0 >> 6], t0 * t0 * invcnt[seg0]);
            if (has1) {
                float t1 = fmaxf(d11 - 0.5f, 0.f);
                atomicAdd(&lp[seg1 >> 6], t1 * t1 * invcnt[seg1]);
            }
        }
    }
    __syncthreads();
    if (threadIdx.x < NSB) atomicAdd(&Lpull[threadIdx.x], lp[threadIdx.x]);
}

// ---------------- k6: final combine (Lpull still needs /M) ----------------
__global__ void k_final(const float* __restrict__ Lpull, const float* __restrict__ pushv,
                        const float* __restrict__ Mvals, float* __restrict__ outv, int n) {
    if (threadIdx.x == 0 && blockIdx.x == 0) {
        float loss = 0.0f;
        for (int s = 0; s < NSB; s++) {
            float M = Mvals[s];
            if (M > 1.0f)
                loss += Lpull[s] / M + pushv[s] / fmaxf(M * (M - 1.0f), 1.0f);
        }
        outv[0] = loss / (float)n;
    }
}

extern "C" void kernel_launch(void* const* d_in, const int* in_sizes, int n_in,
                              void* d_out, int out_size, void* d_ws, size_t ws_size,
                              hipStream_t stream) {
    const float* outp = (const float*)d_in[0];
    const int* labels = (const int*)d_in[1];
    const int* sbidx = (const int*)d_in[2];
    float* out = (float*)d_out;
    int n = in_sizes[1];

    // workspace layout
    float* partials = (float*)d_ws;                       // NSEG*BPS*DIM
    float* mus = partials + (size_t)NSEG * BPS * DIM;     // NSEG*DIM
    int* sorted = (int*)(mus + (size_t)NSEG * DIM);       // n
    int* counts = sorted + n;                             // 512  -- zeroed
    int* done = counts + NSEG;                            // 1    -- zeroed
    float* Lpull = (float*)(done + 1);                    // 8    -- zeroed
    float* pushv = Lpull + NSB;                           // 8    -- zeroed
    int* offsets = (int*)(pushv + NSB);                   // 512
    int* cursors = offsets + NSEG;                        // 512
    float* Mvals = (float*)(cursors + NSEG);              // 8
    float* invcnt = Mvals + NSB;                          // 512

    hipMemsetAsync(counts, 0, (NSEG + 1 + 2 * NSB) * 4, stream);

    k_hist<<<256, 256, 0, stream>>>(labels, sbidx, counts, done, offsets, cursors, Mvals, invcnt, n);
    k_scatter<<<256, 256, 0, stream>>>(labels, sbidx, cursors, sorted, n);
    k_accum<<<NSEG * BPS, 256, 0, stream>>>(outp, sorted, offsets, counts, partials);
    k_push<<<NSB * 16, 256, 0, stream>>>(partials, counts, mus, pushv);
    k_pull<<<2048, 256, 0, stream>>>(outp, labels, sbidx, mus, invcnt, Lpull, n);
    k_final<<<1, 64, 0, stream>>>(Lpull, pushv, Mvals, out, n);
}

// Round 4
// 224.933 us; speedup vs baseline: 1.0281x; 1.0281x over previous
//
#include <hip/hip_runtime.h>
#include <hip/hip_bf16.h>

#define DIM 256
#define NSB 8
#define NLBL 64
#define NSEG (NSB * NLBL)
#define BPS 4   // blocks per segment for accum

// ---------------- k1: histogram (LDS bins) + fused last-block scan ----------------
__global__ void k_hist(const int* __restrict__ labels, const int* __restrict__ sbidx,
                       int* __restrict__ counts, int* __restrict__ done,
                       int* __restrict__ offsets, int* __restrict__ cursors,
                       float* __restrict__ Mvals, float* __restrict__ invcnt, int n) {
    __shared__ int bins[NSEG];
    __shared__ int lastFlag;
    for (int i = threadIdx.x; i < NSEG; i += blockDim.x) bins[i] = 0;
    __syncthreads();
    int t4 = blockIdx.x * blockDim.x + threadIdx.x;
    int stride4 = gridDim.x * blockDim.x;
    for (int q = t4; q * 4 < n; q += stride4) {
        int4 lb = reinterpret_cast<const int4*>(labels)[q];
        int4 sb = reinterpret_cast<const int4*>(sbidx)[q];
        atomicAdd(&bins[sb.x * NLBL + lb.x], 1);
        atomicAdd(&bins[sb.y * NLBL + lb.y], 1);
        atomicAdd(&bins[sb.z * NLBL + lb.z], 1);
        atomicAdd(&bins[sb.w * NLBL + lb.w], 1);
    }
    __syncthreads();
    for (int i = threadIdx.x; i < NSEG; i += blockDim.x)
        if (bins[i] > 0) atomicAdd(&counts[i], bins[i]);
    __syncthreads();
    if (threadIdx.x == 0) {
        __threadfence();
        int t = atomicAdd(done, 1);
        lastFlag = (t == (int)gridDim.x - 1) ? 1 : 0;
    }
    __syncthreads();
    if (!lastFlag) return;
    if (threadIdx.x < 64) {       // exclusive scan over 512 counts, one wave
        int lane = threadIdx.x;
        int carry = 0;
        for (int c = 0; c < NSB; c++) {
            int idx = c * 64 + lane;
            int v = atomicAdd(&counts[idx], 0);   // coherent read (cross-XCD)
            int incl = v;
            #pragma unroll
            for (int m = 1; m < 64; m <<= 1) {
                int t2 = __shfl_up(incl, m, 64);
                if (lane >= m) incl += t2;
            }
            int excl = carry + incl - v;
            offsets[idx] = excl;
            cursors[idx] = excl;
            invcnt[idx] = 1.0f / fmaxf((float)v, 1.0f);
            carry += __shfl(incl, 63, 64);
            unsigned long long b = __ballot(v > 0);
            if (lane == 0) Mvals[c] = (float)__popcll(b);
        }
    }
}

// ---------------- k2: scatter point indices into sorted order ----------------
__global__ void k_scatter(const int* __restrict__ labels, const int* __restrict__ sbidx,
                          int* __restrict__ cursors, int* __restrict__ sorted, int n) {
    int t = blockIdx.x * blockDim.x + threadIdx.x;
    int stride = gridDim.x * blockDim.x;
    for (int q = t; q * 4 < n; q += stride) {
        int4 lb = reinterpret_cast<const int4*>(labels)[q];
        int4 sb = reinterpret_cast<const int4*>(sbidx)[q];
        int p = q * 4;
        sorted[atomicAdd(&cursors[sb.x * NLBL + lb.x], 1)] = p;
        sorted[atomicAdd(&cursors[sb.y * NLBL + lb.y], 1)] = p + 1;
        sorted[atomicAdd(&cursors[sb.z * NLBL + lb.z], 1)] = p + 2;
        sorted[atomicAdd(&cursors[sb.w * NLBL + lb.w], 1)] = p + 3;
    }
}

// ---------------- k3: gather rows, normalize, accumulate; 4-deep pipeline; writes rnorm ----------------
__global__ void k_accum(const float* __restrict__ outp, const int* __restrict__ sorted,
                        const int* __restrict__ offsets, const int* __restrict__ counts,
                        float* __restrict__ partials, float* __restrict__ rnorm) {
    int seg = blockIdx.x >> 2;       // BPS = 4
    int part = blockIdx.x & 3;
    int base = offsets[seg], cnt = counts[seg];
    int chunk = (cnt + BPS - 1) / BPS;
    int lo = base + part * chunk;
    int hi = min(base + cnt, lo + chunk);
    int wv = threadIdx.x >> 6, lane = threadIdx.x & 63;
    float4 acc = {0.f, 0.f, 0.f, 0.f};
    int i = lo + wv * 4;
    int p0 = (i + 0 < hi) ? sorted[i + 0] : -1;
    int p1 = (i + 1 < hi) ? sorted[i + 1] : -1;
    int p2 = (i + 2 < hi) ? sorted[i + 2] : -1;
    int p3 = (i + 3 < hi) ? sorted[i + 3] : -1;
    for (; i < hi; i += 16) {
        int ni = i + 16;
        int q0 = (ni + 0 < hi) ? sorted[ni + 0] : -1;   // prefetch next ids
        int q1 = (ni + 1 < hi) ? sorted[ni + 1] : -1;
        int q2 = (ni + 2 < hi) ? sorted[ni + 2] : -1;
        int q3 = (ni + 3 < hi) ? sorted[ni + 3] : -1;
        float4 v0 = {0.f,0.f,0.f,0.f}, v1 = {0.f,0.f,0.f,0.f};
        float4 v2 = {0.f,0.f,0.f,0.f}, v3 = {0.f,0.f,0.f,0.f};
        v0 = *reinterpret_cast<const float4*>(outp + (size_t)p0 * DIM + lane * 4);
        if (p1 >= 0) v1 = *reinterpret_cast<const float4*>(outp + (size_t)p1 * DIM + lane * 4);
        if (p2 >= 0) v2 = *reinterpret_cast<const float4*>(outp + (size_t)p2 * DIM + lane * 4);
        if (p3 >= 0) v3 = *reinterpret_cast<const float4*>(outp + (size_t)p3 * DIM + lane * 4);
        float s0 = v0.x*v0.x + v0.y*v0.y + v0.z*v0.z + v0.w*v0.w;
        float s1 = v1.x*v1.x + v1.y*v1.y + v1.z*v1.z + v1.w*v1.w;
        float s2 = v2.x*v2.x + v2.y*v2.y + v2.z*v2.z + v2.w*v2.w;
        float s3 = v3.x*v3.x + v3.y*v3.y + v3.z*v3.z + v3.w*v3.w;
        #pragma unroll
        for (int m = 32; m >= 1; m >>= 1) {   // 4 interleaved trees
            s0 += __shfl_xor(s0, m, 64);
            s1 += __shfl_xor(s1, m, 64);
            s2 += __shfl_xor(s2, m, 64);
            s3 += __shfl_xor(s3, m, 64);
        }
        float r0 = 1.0f / (sqrtf(s0) + 1e-8f);
        float r1 = 1.0f / (sqrtf(s1) + 1e-8f);
        float r2 = 1.0f / (sqrtf(s2) + 1e-8f);
        float r3 = 1.0f / (sqrtf(s3) + 1e-8f);
        if (lane == 0) {                       // persist norms for the pull pass
            rnorm[p0] = r0;
            if (p1 >= 0) rnorm[p1] = r1;
            if (p2 >= 0) rnorm[p2] = r2;
            if (p3 >= 0) rnorm[p3] = r3;
        }
        acc.x += v0.x*r0 + v1.x*r1 + v2.x*r2 + v3.x*r3;  // zero rows contribute 0
        acc.y += v0.y*r0 + v1.y*r1 + v2.y*r2 + v3.y*r3;
        acc.z += v0.z*r0 + v1.z*r1 + v2.z*r2 + v3.z*r3;
        acc.w += v0.w*r0 + v1.w*r1 + v2.w*r2 + v3.w*r3;
        p0 = q0; p1 = q1; p2 = q2; p3 = q3;
    }
    __shared__ float pl[4][DIM];
    pl[wv][lane * 4 + 0] = acc.x;
    pl[wv][lane * 4 + 1] = acc.y;
    pl[wv][lane * 4 + 2] = acc.z;
    pl[wv][lane * 4 + 3] = acc.w;
    __syncthreads();
    int t = threadIdx.x;
    partials[(size_t)blockIdx.x * DIM + t] = pl[0][t] + pl[1][t] + pl[2][t] + pl[3][t];
}

// ---------------- k4: push term (mu recomputed from partials; chunk 0 materializes mus) ----------------
__global__ void k_push(const float* __restrict__ partials, const int* __restrict__ counts,
                       float* __restrict__ mus, float* __restrict__ pushv) {
    __shared__ float lds[NLBL][DIM + 1];
    int s = blockIdx.x >> 4;
    int chunk = blockIdx.x & 15;
    for (int i = threadIdx.x; i < NLBL * DIM; i += 256) {
        int r = i >> 8, d = i & 255;
        int segid = s * NLBL + r;
        const float* pp = partials + (size_t)segid * BPS * DIM + d;
        float sum = pp[0] + pp[DIM] + pp[2 * DIM] + pp[3 * DIM];
        float mu = sum / fmaxf((float)counts[segid], 1.0f);
        lds[r][d] = mu;
        if (chunk == 0) mus[(size_t)segid * DIM + d] = mu;
    }
    __syncthreads();
    int pair = chunk * 256 + threadIdx.x;
    int l1 = pair >> 6, l2 = pair & 63;
    float dist = 0.0f;
    #pragma unroll 8
    for (int d = 0; d < DIM; d++) dist += fabsf(lds[l1][d] - lds[l2][d]);
    float v = fmaxf(3.0f - dist, 0.0f);   // 2*DELTA_D
    v = v * v;
    bool ok = (l1 != l2) && (counts[s * NLBL + l1] > 0) && (counts[s * NLBL + l2] > 0);
    v = ok ? v : 0.0f;
    #pragma unroll
    for (int m = 32; m >= 1; m >>= 1) v += __shfl_xor(v, m, 64);
    __shared__ float wsum[4];
    if ((threadIdx.x & 63) == 0) wsum[threadIdx.x >> 6] = v;
    __syncthreads();
    if (threadIdx.x == 0) atomicAdd(&pushv[s], wsum[0] + wsum[1] + wsum[2] + wsum[3]);
}

// ---------------- k5: pull, natural-order stream, 4-deep, rnorm from memory (no ss chain) ----------------
__global__ void k_pull(const float* __restrict__ outp, const int* __restrict__ labels,
                       const int* __restrict__ sbidx, const float* __restrict__ rnorm,
                       const float* __restrict__ mus, const float* __restrict__ invcnt,
                       float* __restrict__ Lpull, int n) {
    __shared__ float lp[NSB];
    if (threadIdx.x < NSB) lp[threadIdx.x] = 0.f;
    __syncthreads();
    int w = (blockIdx.x * blockDim.x + threadIdx.x) >> 6;
    int lane = threadIdx.x & 63;
    int nw = (gridDim.x * blockDim.x) >> 6;
    int step = nw * 4;
    int pbase = w * 4;
    int l0 = 0, l1 = 0, l2 = 0, l3 = 0, s0 = 0, s1 = 0, s2 = 0, s3 = 0;
    if (pbase + 0 < n) { l0 = labels[pbase + 0]; s0 = sbidx[pbase + 0]; }
    if (pbase + 1 < n) { l1 = labels[pbase + 1]; s1 = sbidx[pbase + 1]; }
    if (pbase + 2 < n) { l2 = labels[pbase + 2]; s2 = sbidx[pbase + 2]; }
    if (pbase + 3 < n) { l3 = labels[pbase + 3]; s3 = sbidx[pbase + 3]; }
    for (; pbase < n; pbase += step) {
        int g0 = s0 * NLBL + l0, g1 = s1 * NLBL + l1;
        int g2 = s2 * NLBL + l2, g3 = s3 * NLBL + l3;
        bool k1 = pbase + 1 < n, k2 = pbase + 2 < n, k3 = pbase + 3 < n;
        float4 x0 = *reinterpret_cast<const float4*>(outp + (size_t)(pbase + 0) * DIM + lane * 4);
        float4 x1 = {0.f,0.f,0.f,0.f}, x2 = {0.f,0.f,0.f,0.f}, x3 = {0.f,0.f,0.f,0.f};
        if (k1) x1 = *reinterpret_cast<const float4*>(outp + (size_t)(pbase + 1) * DIM + lane * 4);
        if (k2) x2 = *reinterpret_cast<const float4*>(outp + (size_t)(pbase + 2) * DIM + lane * 4);
        if (k3) x3 = *reinterpret_cast<const float4*>(outp + (size_t)(pbase + 3) * DIM + lane * 4);
        float4 m0 = *reinterpret_cast<const float4*>(mus + (size_t)g0 * DIM + lane * 4);
        float4 m1 = *reinterpret_cast<const float4*>(mus + (size_t)g1 * DIM + lane * 4);
        float4 m2 = *reinterpret_cast<const float4*>(mus + (size_t)g2 * DIM + lane * 4);
        float4 m3 = *reinterpret_cast<const float4*>(mus + (size_t)g3 * DIM + lane * 4);
        float r0 = rnorm[pbase + 0];
        float r1 = k1 ? rnorm[pbase + 1] : 0.f;
        float r2 = k2 ? rnorm[pbase + 2] : 0.f;
        float r3 = k3 ? rnorm[pbase + 3] : 0.f;
        float c0 = invcnt[g0], c1 = invcnt[g1], c2 = invcnt[g2], c3 = invcnt[g3];
        int nb = pbase + step;                       // prefetch next ids (independent)
        if (nb + 0 < n) { l0 = labels[nb + 0]; s0 = sbidx[nb + 0]; }
        if (nb + 1 < n) { l1 = labels[nb + 1]; s1 = sbidx[nb + 1]; }
        if (nb + 2 < n) { l2 = labels[nb + 2]; s2 = sbidx[nb + 2]; }
        if (nb + 3 < n) { l3 = labels[nb + 3]; s3 = sbidx[nb + 3]; }
        float d0 = fabsf(m0.x - x0.x*r0) + fabsf(m0.y - x0.y*r0) + fabsf(m0.z - x0.z*r0) + fabsf(m0.w - x0.w*r0);
        float d1 = fabsf(m1.x - x1.x*r1) + fabsf(m1.y - x1.y*r1) + fabsf(m1.z - x1.z*r1) + fabsf(m1.w - x1.w*r1);
        float d2 = fabsf(m2.x - x2.x*r2) + fabsf(m2.y - x2.y*r2) + fabsf(m2.z - x2.z*r2) + fabsf(m2.w - x2.w*r2);
        float d3 = fabsf(m3.x - x3.x*r3) + fabsf(m3.y - x3.y*r3) + fabsf(m3.z - x3.z*r3) + fabsf(m3.w - x3.w*r3);
        #pragma unroll
        for (int m = 32; m >= 1; m >>= 1) {   // 4 interleaved trees
            d0 += __shfl_xor(d0, m, 64);
            d1 += __shfl_xor(d1, m, 64);
            d2 += __shfl_xor(d2, m, 64);
            d3 += __shfl_xor(d3, m, 64);
        }
        if (lane == 0) {
            float t0 = fmaxf(d0 - 0.5f, 0.f);            // DELTA_V
            atomicAdd(&lp[g0 >> 6], t0 * t0 * c0);
            if (k1) { float t = fmaxf(d1 - 0.5f, 0.f); atomicAdd(&lp[g1 >> 6], t * t * c1); }
            if (k2) { float t = fmaxf(d2 - 0.5f, 0.f); atomicAdd(&lp[g2 >> 6], t * t * c2); }
            if (k3) { float t = fmaxf(d3 - 0.5f, 0.f); atomicAdd(&lp[g3 >> 6], t * t * c3); }
        }
    }
    __syncthreads();
    if (threadIdx.x < NSB) atomicAdd(&Lpull[threadIdx.x], lp[threadIdx.x]);
}

// ---------------- k6: final combine (Lpull still needs /M) ----------------
__global__ void k_final(const float* __restrict__ Lpull, const float* __restrict__ pushv,
                        const float* __restrict__ Mvals, float* __restrict__ outv, int n) {
    if (threadIdx.x == 0 && blockIdx.x == 0) {
        float loss = 0.0f;
        for (int s = 0; s < NSB; s++) {
            float M = Mvals[s];
            if (M > 1.0f)
                loss += Lpull[s] / M + pushv[s] / fmaxf(M * (M - 1.0f), 1.0f);
        }
        outv[0] = loss / (float)n;
    }
}

extern "C" void kernel_launch(void* const* d_in, const int* in_sizes, int n_in,
                              void* d_out, int out_size, void* d_ws, size_t ws_size,
                              hipStream_t stream) {
    const float* outp = (const float*)d_in[0];
    const int* labels = (const int*)d_in[1];
    const int* sbidx = (const int*)d_in[2];
    float* out = (float*)d_out;
    int n = in_sizes[1];

    // workspace layout
    float* partials = (float*)d_ws;                       // NSEG*BPS*DIM
    float* mus = partials + (size_t)NSEG * BPS * DIM;     // NSEG*DIM
    int* sorted = (int*)(mus + (size_t)NSEG * DIM);       // n
    float* rnorm = (float*)(sorted + n);                  // n
    int* counts = (int*)(rnorm + n);                      // 512  -- zeroed
    int* done = counts + NSEG;                            // 1    -- zeroed
    float* Lpull = (float*)(done + 1);                    // 8    -- zeroed
    float* pushv = Lpull + NSB;                           // 8    -- zeroed
    int* offsets = (int*)(pushv + NSB);                   // 512
    int* cursors = offsets + NSEG;                        // 512
    float* Mvals = (float*)(cursors + NSEG);              // 8
    float* invcnt = Mvals + NSB;                          // 512

    hipMemsetAsync(counts, 0, (NSEG + 1 + 2 * NSB) * 4, stream);

    k_hist<<<256, 256, 0, stream>>>(labels, sbidx, counts, done, offsets, cursors, Mvals, invcnt, n);
    k_scatter<<<256, 256, 0, stream>>>(labels, sbidx, cursors, sorted, n);
    k_accum<<<NSEG * BPS, 256, 0, stream>>>(outp, sorted, offsets, counts, partials, rnorm);
    k_push<<<NSB * 16, 256, 0, stream>>>(partials, counts, mus, pushv);
    k_pull<<<2048, 256, 0, stream>>>(outp, labels, sbidx, rnorm, mus, invcnt, Lpull, n);
    k_final<<<1, 64, 0, stream>>>(Lpull, pushv, Mvals, out, n);
}

// Round 5
// 220.279 us; speedup vs baseline: 1.0498x; 1.0211x over previous
//
#include <hip/hip_runtime.h>
#include <hip/hip_bf16.h>

#define DIM 256
#define NSB 8
#define NLBL 64
#define NSEG (NSB * NLBL)
#define BPS 4    // blocks per segment for accum
#define NBH 128  // histogram blocks

// ---------------- k1: per-block histogram, plain stores (NO pre-zeroed globals) ----------------
__global__ void k_hist(const int* __restrict__ labels, const int* __restrict__ sbidx,
                       int* __restrict__ blockBins, int n) {
    __shared__ int bins[NSEG];
    for (int i = threadIdx.x; i < NSEG; i += blockDim.x) bins[i] = 0;
    __syncthreads();
    int t4 = blockIdx.x * blockDim.x + threadIdx.x;
    int stride4 = gridDim.x * blockDim.x;
    for (int q = t4; q * 4 < n; q += stride4) {
        int4 lb = reinterpret_cast<const int4*>(labels)[q];
        int4 sb = reinterpret_cast<const int4*>(sbidx)[q];
        atomicAdd(&bins[sb.x * NLBL + lb.x], 1);
        atomicAdd(&bins[sb.y * NLBL + lb.y], 1);
        atomicAdd(&bins[sb.z * NLBL + lb.z], 1);
        atomicAdd(&bins[sb.w * NLBL + lb.w], 1);
    }
    __syncthreads();
    for (int i = threadIdx.x; i < NSEG; i += blockDim.x)
        blockBins[blockIdx.x * NSEG + i] = bins[i];
}

// ---------------- k2: reduce bins + scan + all tiny init (replaces memset node) ----------------
__global__ void k_scan(const int* __restrict__ blockBins, int* __restrict__ counts,
                       int* __restrict__ offsets, int* __restrict__ cursors,
                       float* __restrict__ Mvals, float* __restrict__ invcnt,
                       float* __restrict__ Lpull, float* __restrict__ pushv) {
    __shared__ int cnt[NSEG];
    int t = threadIdx.x;          // 512 threads, one per segment
    int sum = 0;
    #pragma unroll 4
    for (int b = 0; b < NBH; b++) sum += blockBins[b * NSEG + t];
    cnt[t] = sum;
    counts[t] = sum;
    invcnt[t] = 1.0f / fmaxf((float)sum, 1.0f);
    if (t < NSB) { Lpull[t] = 0.f; pushv[t] = 0.f; }
    __syncthreads();
    if (t < 64) {                 // exclusive scan over 512 counts, one wave
        int lane = t;
        int carry = 0;
        for (int c = 0; c < NSB; c++) {
            int idx = c * 64 + lane;
            int v = cnt[idx];
            int incl = v;
            #pragma unroll
            for (int m = 1; m < 64; m <<= 1) {
                int t2 = __shfl_up(incl, m, 64);
                if (lane >= m) incl += t2;
            }
            int excl = carry + incl - v;
            offsets[idx] = excl;
            cursors[idx] = excl;
            carry += __shfl(incl, 63, 64);
            unsigned long long b = __ballot(v > 0);
            if (lane == 0) Mvals[c] = (float)__popcll(b);
        }
    }
}

// ---------------- k3: scatter point indices into sorted order ----------------
__global__ void k_scatter(const int* __restrict__ labels, const int* __restrict__ sbidx,
                          int* __restrict__ cursors, int* __restrict__ sorted, int n) {
    int t = blockIdx.x * blockDim.x + threadIdx.x;
    int stride = gridDim.x * blockDim.x;
    for (int q = t; q * 4 < n; q += stride) {
        int4 lb = reinterpret_cast<const int4*>(labels)[q];
        int4 sb = reinterpret_cast<const int4*>(sbidx)[q];
        int p = q * 4;
        sorted[atomicAdd(&cursors[sb.x * NLBL + lb.x], 1)] = p;
        sorted[atomicAdd(&cursors[sb.y * NLBL + lb.y], 1)] = p + 1;
        sorted[atomicAdd(&cursors[sb.z * NLBL + lb.z], 1)] = p + 2;
        sorted[atomicAdd(&cursors[sb.w * NLBL + lb.w], 1)] = p + 3;
    }
}

// ---------------- k4: gather rows, normalize, accumulate; 4-deep pipeline; writes rnorm ----------------
__global__ void k_accum(const float* __restrict__ outp, const int* __restrict__ sorted,
                        const int* __restrict__ offsets, const int* __restrict__ counts,
                        float* __restrict__ partials, float* __restrict__ rnorm) {
    int seg = blockIdx.x >> 2;       // BPS = 4
    int part = blockIdx.x & 3;
    int base = offsets[seg], cnt = counts[seg];
    int chunk = (cnt + BPS - 1) / BPS;
    int lo = base + part * chunk;
    int hi = min(base + cnt, lo + chunk);
    int wv = threadIdx.x >> 6, lane = threadIdx.x & 63;
    float4 acc = {0.f, 0.f, 0.f, 0.f};
    int i = lo + wv * 4;
    int p0 = (i + 0 < hi) ? sorted[i + 0] : -1;
    int p1 = (i + 1 < hi) ? sorted[i + 1] : -1;
    int p2 = (i + 2 < hi) ? sorted[i + 2] : -1;
    int p3 = (i + 3 < hi) ? sorted[i + 3] : -1;
    for (; i < hi; i += 16) {
        int ni = i + 16;
        int q0 = (ni + 0 < hi) ? sorted[ni + 0] : -1;   // prefetch next ids
        int q1 = (ni + 1 < hi) ? sorted[ni + 1] : -1;
        int q2 = (ni + 2 < hi) ? sorted[ni + 2] : -1;
        int q3 = (ni + 3 < hi) ? sorted[ni + 3] : -1;
        float4 v0 = {0.f,0.f,0.f,0.f}, v1 = {0.f,0.f,0.f,0.f};
        float4 v2 = {0.f,0.f,0.f,0.f}, v3 = {0.f,0.f,0.f,0.f};
        v0 = *reinterpret_cast<const float4*>(outp + (size_t)p0 * DIM + lane * 4);
        if (p1 >= 0) v1 = *reinterpret_cast<const float4*>(outp + (size_t)p1 * DIM + lane * 4);
        if (p2 >= 0) v2 = *reinterpret_cast<const float4*>(outp + (size_t)p2 * DIM + lane * 4);
        if (p3 >= 0) v3 = *reinterpret_cast<const float4*>(outp + (size_t)p3 * DIM + lane * 4);
        float s0 = v0.x*v0.x + v0.y*v0.y + v0.z*v0.z + v0.w*v0.w;
        float s1 = v1.x*v1.x + v1.y*v1.y + v1.z*v1.z + v1.w*v1.w;
        float s2 = v2.x*v2.x + v2.y*v2.y + v2.z*v2.z + v2.w*v2.w;
        float s3 = v3.x*v3.x + v3.y*v3.y + v3.z*v3.z + v3.w*v3.w;
        #pragma unroll
        for (int m = 32; m >= 1; m >>= 1) {   // 4 interleaved trees
            s0 += __shfl_xor(s0, m, 64);
            s1 += __shfl_xor(s1, m, 64);
            s2 += __shfl_xor(s2, m, 64);
            s3 += __shfl_xor(s3, m, 64);
        }
        float r0 = 1.0f / (sqrtf(s0) + 1e-8f);
        float r1 = 1.0f / (sqrtf(s1) + 1e-8f);
        float r2 = 1.0f / (sqrtf(s2) + 1e-8f);
        float r3 = 1.0f / (sqrtf(s3) + 1e-8f);
        if (lane == 0) {                       // persist norms for the pull pass
            rnorm[p0] = r0;
            if (p1 >= 0) rnorm[p1] = r1;
            if (p2 >= 0) rnorm[p2] = r2;
            if (p3 >= 0) rnorm[p3] = r3;
        }
        acc.x += v0.x*r0 + v1.x*r1 + v2.x*r2 + v3.x*r3;  // zero rows contribute 0
        acc.y += v0.y*r0 + v1.y*r1 + v2.y*r2 + v3.y*r3;
        acc.z += v0.z*r0 + v1.z*r1 + v2.z*r2 + v3.z*r3;
        acc.w += v0.w*r0 + v1.w*r1 + v2.w*r2 + v3.w*r3;
        p0 = q0; p1 = q1; p2 = q2; p3 = q3;
    }
    __shared__ float pl[4][DIM];
    pl[wv][lane * 4 + 0] = acc.x;
    pl[wv][lane * 4 + 1] = acc.y;
    pl[wv][lane * 4 + 2] = acc.z;
    pl[wv][lane * 4 + 3] = acc.w;
    __syncthreads();
    int t = threadIdx.x;
    partials[(size_t)blockIdx.x * DIM + t] = pl[0][t] + pl[1][t] + pl[2][t] + pl[3][t];
}

// ---------------- k5: push term (mu recomputed from partials; chunk 0 materializes mus) ----------------
__global__ void k_push(const float* __restrict__ partials, const int* __restrict__ counts,
                       float* __restrict__ mus, float* __restrict__ pushv) {
    __shared__ float lds[NLBL][DIM + 1];
    int s = blockIdx.x >> 4;
    int chunk = blockIdx.x & 15;
    for (int i = threadIdx.x; i < NLBL * DIM; i += 256) {
        int r = i >> 8, d = i & 255;
        int segid = s * NLBL + r;
        const float* pp = partials + (size_t)segid * BPS * DIM + d;
        float sum = pp[0] + pp[DIM] + pp[2 * DIM] + pp[3 * DIM];
        float mu = sum / fmaxf((float)counts[segid], 1.0f);
        lds[r][d] = mu;
        if (chunk == 0) mus[(size_t)segid * DIM + d] = mu;
    }
    __syncthreads();
    int pair = chunk * 256 + threadIdx.x;
    int l1 = pair >> 6, l2 = pair & 63;
    float dist = 0.0f;
    #pragma unroll 8
    for (int d = 0; d < DIM; d++) dist += fabsf(lds[l1][d] - lds[l2][d]);
    float v = fmaxf(3.0f - dist, 0.0f);   // 2*DELTA_D
    v = v * v;
    bool ok = (l1 != l2) && (counts[s * NLBL + l1] > 0) && (counts[s * NLBL + l2] > 0);
    v = ok ? v : 0.0f;
    #pragma unroll
    for (int m = 32; m >= 1; m >>= 1) v += __shfl_xor(v, m, 64);
    __shared__ float wsum[4];
    if ((threadIdx.x & 63) == 0) wsum[threadIdx.x >> 6] = v;
    __syncthreads();
    if (threadIdx.x == 0) atomicAdd(&pushv[s], wsum[0] + wsum[1] + wsum[2] + wsum[3]);
}

// ---------------- k6: pull, natural-order stream, 4-deep, rnorm from memory ----------------
__global__ void k_pull(const float* __restrict__ outp, const int* __restrict__ labels,
                       const int* __restrict__ sbidx, const float* __restrict__ rnorm,
                       const float* __restrict__ mus, const float* __restrict__ invcnt,
                       float* __restrict__ Lpull, int n) {
    __shared__ float lp[NSB];
    if (threadIdx.x < NSB) lp[threadIdx.x] = 0.f;
    __syncthreads();
    int w = (blockIdx.x * blockDim.x + threadIdx.x) >> 6;
    int lane = threadIdx.x & 63;
    int nw = (gridDim.x * blockDim.x) >> 6;
    int step = nw * 4;
    int pbase = w * 4;
    int l0 = 0, l1 = 0, l2 = 0, l3 = 0, s0 = 0, s1 = 0, s2 = 0, s3 = 0;
    if (pbase + 0 < n) { l0 = labels[pbase + 0]; s0 = sbidx[pbase + 0]; }
    if (pbase + 1 < n) { l1 = labels[pbase + 1]; s1 = sbidx[pbase + 1]; }
    if (pbase + 2 < n) { l2 = labels[pbase + 2]; s2 = sbidx[pbase + 2]; }
    if (pbase + 3 < n) { l3 = labels[pbase + 3]; s3 = sbidx[pbase + 3]; }
    for (; pbase < n; pbase += step) {
        int g0 = s0 * NLBL + l0, g1 = s1 * NLBL + l1;
        int g2 = s2 * NLBL + l2, g3 = s3 * NLBL + l3;
        bool k1 = pbase + 1 < n, k2 = pbase + 2 < n, k3 = pbase + 3 < n;
        float4 x0 = *reinterpret_cast<const float4*>(outp + (size_t)(pbase + 0) * DIM + lane * 4);
        float4 x1 = {0.f,0.f,0.f,0.f}, x2 = {0.f,0.f,0.f,0.f}, x3 = {0.f,0.f,0.f,0.f};
        if (k1) x1 = *reinterpret_cast<const float4*>(outp + (size_t)(pbase + 1) * DIM + lane * 4);
        if (k2) x2 = *reinterpret_cast<const float4*>(outp + (size_t)(pbase + 2) * DIM + lane * 4);
        if (k3) x3 = *reinterpret_cast<const float4*>(outp + (size_t)(pbase + 3) * DIM + lane * 4);
        float4 m0 = *reinterpret_cast<const float4*>(mus + (size_t)g0 * DIM + lane * 4);
        float4 m1 = *reinterpret_cast<const float4*>(mus + (size_t)g1 * DIM + lane * 4);
        float4 m2 = *reinterpret_cast<const float4*>(mus + (size_t)g2 * DIM + lane * 4);
        float4 m3 = *reinterpret_cast<const float4*>(mus + (size_t)g3 * DIM + lane * 4);
        float r0 = rnorm[pbase + 0];
        float r1 = k1 ? rnorm[pbase + 1] : 0.f;
        float r2 = k2 ? rnorm[pbase + 2] : 0.f;
        float r3 = k3 ? rnorm[pbase + 3] : 0.f;
        float c0 = invcnt[g0], c1 = invcnt[g1], c2 = invcnt[g2], c3 = invcnt[g3];
        int nb = pbase + step;                       // prefetch next ids (independent)
        if (nb + 0 < n) { l0 = labels[nb + 0]; s0 = sbidx[nb + 0]; }
        if (nb + 1 < n) { l1 = labels[nb + 1]; s1 = sbidx[nb + 1]; }
        if (nb + 2 < n) { l2 = labels[nb + 2]; s2 = sbidx[nb + 2]; }
        if (nb + 3 < n) { l3 = labels[nb + 3]; s3 = sbidx[nb + 3]; }
        float d0 = fabsf(m0.x - x0.x*r0) + fabsf(m0.y - x0.y*r0) + fabsf(m0.z - x0.z*r0) + fabsf(m0.w - x0.w*r0);
        float d1 = fabsf(m1.x - x1.x*r1) + fabsf(m1.y - x1.y*r1) + fabsf(m1.z - x1.z*r1) + fabsf(m1.w - x1.w*r1);
        float d2 = fabsf(m2.x - x2.x*r2) + fabsf(m2.y - x2.y*r2) + fabsf(m2.z - x2.z*r2) + fabsf(m2.w - x2.w*r2);
        float d3 = fabsf(m3.x - x3.x*r3) + fabsf(m3.y - x3.y*r3) + fabsf(m3.z - x3.z*r3) + fabsf(m3.w - x3.w*r3);
        #pragma unroll
        for (int m = 32; m >= 1; m >>= 1) {   // 4 interleaved trees
            d0 += __shfl_xor(d0, m, 64);
            d1 += __shfl_xor(d1, m, 64);
            d2 += __shfl_xor(d2, m, 64);
            d3 += __shfl_xor(d3, m, 64);
        }
        if (lane == 0) {
            float t0 = fmaxf(d0 - 0.5f, 0.f);            // DELTA_V
            atomicAdd(&lp[g0 >> 6], t0 * t0 * c0);
            if (k1) { float t = fmaxf(d1 - 0.5f, 0.f); atomicAdd(&lp[g1 >> 6], t * t * c1); }
            if (k2) { float t = fmaxf(d2 - 0.5f, 0.f); atomicAdd(&lp[g2 >> 6], t * t * c2); }
            if (k3) { float t = fmaxf(d3 - 0.5f, 0.f); atomicAdd(&lp[g3 >> 6], t * t * c3); }
        }
    }
    __syncthreads();
    if (threadIdx.x < NSB) atomicAdd(&Lpull[threadIdx.x], lp[threadIdx.x]);
}

// ---------------- k7: final combine (Lpull still needs /M) ----------------
__global__ void k_final(const float* __restrict__ Lpull, const float* __restrict__ pushv,
                        const float* __restrict__ Mvals, float* __restrict__ outv, int n) {
    if (threadIdx.x == 0 && blockIdx.x == 0) {
        float loss = 0.0f;
        for (int s = 0; s < NSB; s++) {
            float M = Mvals[s];
            if (M > 1.0f)
                loss += Lpull[s] / M + pushv[s] / fmaxf(M * (M - 1.0f), 1.0f);
        }
        outv[0] = loss / (float)n;
    }
}

extern "C" void kernel_launch(void* const* d_in, const int* in_sizes, int n_in,
                              void* d_out, int out_size, void* d_ws, size_t ws_size,
                              hipStream_t stream) {
    const float* outp = (const float*)d_in[0];
    const int* labels = (const int*)d_in[1];
    const int* sbidx = (const int*)d_in[2];
    float* out = (float*)d_out;
    int n = in_sizes[1];

    // workspace layout (NOTHING requires pre-zeroing by the host)
    float* partials = (float*)d_ws;                       // NSEG*BPS*DIM
    float* mus = partials + (size_t)NSEG * BPS * DIM;     // NSEG*DIM
    int* sorted = (int*)(mus + (size_t)NSEG * DIM);       // n
    float* rnorm = (float*)(sorted + n);                  // n
    int* blockBins = (int*)(rnorm + n);                   // NBH*NSEG
    int* counts = blockBins + NBH * NSEG;                 // 512
    int* offsets = counts + NSEG;                         // 512
    int* cursors = offsets + NSEG;                        // 512
    float* invcnt = (float*)(cursors + NSEG);             // 512
    float* Mvals = invcnt + NSEG;                         // 8
    float* Lpull = Mvals + NSB;                           // 8
    float* pushv = Lpull + NSB;                           // 8

    k_hist<<<NBH, 256, 0, stream>>>(labels, sbidx, blockBins, n);
    k_scan<<<1, 512, 0, stream>>>(blockBins, counts, offsets, cursors, Mvals, invcnt, Lpull, pushv);
    k_scatter<<<256, 256, 0, stream>>>(labels, sbidx, cursors, sorted, n);
    k_accum<<<NSEG * BPS, 256, 0, stream>>>(outp, sorted, offsets, counts, partials, rnorm);
    k_push<<<NSB * 16, 256, 0, stream>>>(partials, counts, mus, pushv);
    k_pull<<<2048, 256, 0, stream>>>(outp, labels, sbidx, rnorm, mus, invcnt, Lpull, n);
    k_final<<<1, 64, 0, stream>>>(Lpull, pushv, Mvals, out, n);
}